// Round 27
// baseline (604.204 us; speedup 1.0000x reference)
//
#include <hip/hip_runtime.h>

#define N_  128
#define C_  64
#define T_  128
#define V_  25
#define CO_ 128
#define H_  3
#define D_  16

constexpr int COLS = 3200;
constexpr float EPSF = 1e-5f;

typedef __attribute__((ext_vector_type(8))) short short8;
typedef __attribute__((ext_vector_type(8))) unsigned short ushort8;
typedef __attribute__((ext_vector_type(4))) unsigned short us4v;
typedef __attribute__((ext_vector_type(4))) float f32x4;

// ---- workspace layout (float units) ----
constexpr size_t OFF_ATT  = 0;                          // 240,000
constexpr size_t OFF_BIG  = 240000;                     // time-shared:
//   phase A: qkT bf16 [n][3200][96] (19.7M fl)
//   phase B: TmT bf16 [n][3200][192] (39.3M fl)
constexpr size_t BIGF     = 78643200;
constexpr size_t OFF_X2   = OFF_BIG + BIGF;             // x2T bf16: 26.2M fl
constexpr size_t OFF_W    = OFF_X2 + 26214400;
constexpr size_t OFF_WQHI  = OFF_W;                     // 96*64 us = 3072 fl
constexpr size_t OFF_WA3HI = OFF_WQHI + 3072;           // 128*256 us = 16384 fl
constexpr size_t OFF_WA4HI = OFF_WA3HI + 16384;         // 128*192 us = 12288 fl
constexpr size_t OFF_WA5HI = OFF_WA4HI + 12288;         // 128*1024 us = 65536 fl
constexpr size_t OFF_B3    = OFF_WA5HI + 65536;
constexpr size_t OFF_B4    = OFF_B3 + 128;
constexpr size_t OFF_B5    = OFF_B4 + 128;

__device__ __forceinline__ float lrelu(float y) { return y >= 0.f ? y : 0.1f * y; }

__device__ __forceinline__ unsigned short f2bf_rne(float f) {
    unsigned int u = __builtin_bit_cast(unsigned int, f);
    u += 0x7FFFu + ((u >> 16) & 1u);
    return (unsigned short)(u >> 16);
}
__device__ __forceinline__ float bf2f(unsigned short b) {
    unsigned int u = ((unsigned int)b) << 16;
    return __builtin_bit_cast(float, u);
}

__device__ __forceinline__ void gload_lds16(const unsigned short* g, unsigned short* l) {
    __builtin_amdgcn_global_load_lds(
        (const __attribute__((address_space(1))) unsigned int*)g,
        (__attribute__((address_space(3))) unsigned int*)l,
        16, 0, 0);
}

// ---- K0: BN-fold + bf16 A-operands (single plane) ----
__global__ void k0_prep(const float* __restrict__ w_qkv,
                        const float* __restrict__ w_out, const float* __restrict__ b_out,
                        const float* __restrict__ g_out, const float* __restrict__ be_out,
                        const float* __restrict__ m_out, const float* __restrict__ v_out,
                        const float* __restrict__ w_ff,  const float* __restrict__ b_ff,
                        const float* __restrict__ g_ff,  const float* __restrict__ be_ff,
                        const float* __restrict__ m_ff,  const float* __restrict__ v_ff,
                        const float* __restrict__ w_t,   const float* __restrict__ b_t,
                        const float* __restrict__ g_t,   const float* __restrict__ be_t,
                        const float* __restrict__ m_t,   const float* __restrict__ v_t,
                        const float* __restrict__ w_ress,const float* __restrict__ b_ress,
                        const float* __restrict__ g_ress,const float* __restrict__ be_ress,
                        const float* __restrict__ m_ress,const float* __restrict__ v_ress,
                        const float* __restrict__ w_rest,const float* __restrict__ b_rest,
                        const float* __restrict__ g_rest,const float* __restrict__ be_rest,
                        const float* __restrict__ m_rest,const float* __restrict__ v_rest,
                        float* __restrict__ ws)
{
    int tid = blockIdx.x * blockDim.x + threadIdx.x;
    int np = gridDim.x * blockDim.x;

    unsigned short* wqh = (unsigned short*)(ws + OFF_WQHI);
    for (int idx = tid; idx < 96 * 64; idx += np)
        wqh[idx] = f2bf_rne(w_qkv[idx]);

    unsigned short* w3h = (unsigned short*)(ws + OFF_WA3HI);
    for (int idx = tid; idx < 128 * 256; idx += np) {
        int o = idx >> 8, k = idx & 255;
        float val;
        if (k < 192) {
            float sc = g_out[o] * rsqrtf(v_out[o] + EPSF);
            val = w_out[o * 192 + k] * sc;
        } else {
            float sc = g_ress[o] * rsqrtf(v_ress[o] + EPSF);
            val = w_ress[o * 64 + (k - 192)] * sc;
        }
        w3h[idx] = f2bf_rne(val);
    }

    unsigned short* w4h = (unsigned short*)(ws + OFF_WA4HI);
    for (int idx = tid; idx < 128 * 192; idx += np) {
        int o = idx / 192, k = idx % 192;
        float val;
        if (k < 128) {
            float sc = g_ff[o] * rsqrtf(v_ff[o] + EPSF);
            val = w_ff[o * 128 + k] * sc;
        } else {
            float sc = g_ress[o] * rsqrtf(v_ress[o] + EPSF);
            val = w_ress[o * 64 + (k - 128)] * sc;
        }
        w4h[idx] = f2bf_rne(val);
    }

    unsigned short* w5h = (unsigned short*)(ws + OFF_WA5HI);
    for (int idx = tid; idx < 128 * 1024; idx += np) {
        int o = idx >> 10, kk = idx & 1023;
        int tap = kk >> 7, i = kk & 127;
        float val;
        if (tap < 7) {
            float sc = g_t[o] * rsqrtf(v_t[o] + EPSF);
            val = w_t[((size_t)o * 128 + i) * 7 + tap] * sc;
        } else {
            float sc = g_rest[o] * rsqrtf(v_rest[o] + EPSF);
            val = w_rest[o * 128 + i] * sc;
        }
        w5h[idx] = f2bf_rne(val);
    }

    for (int o = tid; o < 128; o += np) {
        float sco = g_out[o] * rsqrtf(v_out[o] + EPSF);
        float scr = g_ress[o] * rsqrtf(v_ress[o] + EPSF);
        float scf = g_ff[o] * rsqrtf(v_ff[o] + EPSF);
        float sct = g_t[o] * rsqrtf(v_t[o] + EPSF);
        float sce = g_rest[o] * rsqrtf(v_rest[o] + EPSF);
        float bres = (b_ress[o] - m_ress[o]) * scr + be_ress[o];
        ws[OFF_B3 + o] = (b_out[o] - m_out[o]) * sco + be_out[o] + bres;
        ws[OFF_B4 + o] = (b_ff[o] - m_ff[o]) * scf + be_ff[o] + bres;
        ws[OFF_B5 + o] = (b_t[o] - m_t[o]) * sct + be_t[o]
                       + (b_rest[o] - m_rest[o]) * sce + be_rest[o];
    }
}

// ---- k1: qkv GEMM M=96,K=64 -> qkT bf16 [n][3200][96]; x read direct (in-LDS transpose) ----
__global__ __launch_bounds__(256, 2) void k1_mfma(const unsigned short* __restrict__ wqh,
                                                   const float* __restrict__ x,
                                                   const float* __restrict__ b_qkv,
                                                   unsigned short* __restrict__ qkT)
{
    __shared__ unsigned short Ah[96][72];
    __shared__ unsigned short Xt[128][72];
    int blk = blockIdx.x;
    int n = blk / 25, ct = blk % 25;
    int c0 = ct * 128;
    int tid = threadIdx.x, lane = tid & 63, wid = tid >> 6;
    int wm = wid & 1, wn = wid >> 1;
    int rbase = lane & 15, koff = (lane >> 4) * 8;

    for (int e = tid; e < 768; e += 256) {
        int o = e >> 3, g = (e & 7) * 8;
        *(ushort8*)&Ah[o][g] = *(const ushort8*)&wqh[(size_t)o * 64 + g];
    }
    const float* xb = x + (size_t)n * 64 * 3200;
    for (int e = tid; e < 2048; e += 256) {
        int c = e >> 5, f4 = (e & 31) * 4;
        f32x4 v = *(const f32x4*)&xb[(size_t)c * 3200 + c0 + f4];
#pragma unroll
        for (int j = 0; j < 4; ++j)
            Xt[f4 + j][c] = f2bf_rne(v[j]);
    }
    __syncthreads();

    f32x4 acc[3][4];
#pragma unroll
    for (int a = 0; a < 3; ++a)
#pragma unroll
        for (int b = 0; b < 4; ++b) acc[a][b] = (f32x4)0.f;

#pragma unroll
    for (int ks = 0; ks < 2; ++ks) {
        short8 afh[3], bfh[4];
#pragma unroll
        for (int mb = 0; mb < 3; ++mb)
            afh[mb] = *(const short8*)&Ah[wm * 48 + mb * 16 + rbase][ks * 32 + koff];
#pragma unroll
        for (int nb = 0; nb < 4; ++nb)
            bfh[nb] = *(const short8*)&Xt[wn * 64 + nb * 16 + rbase][ks * 32 + koff];
#pragma unroll
        for (int mb = 0; mb < 3; ++mb)
#pragma unroll
            for (int nb = 0; nb < 4; ++nb)
                acc[mb][nb] = __builtin_amdgcn_mfma_f32_16x16x32_bf16(afh[mb], bfh[nb], acc[mb][nb], 0, 0, 0);
    }
#pragma unroll
    for (int mb = 0; mb < 3; ++mb) {
#pragma unroll
        for (int nb = 0; nb < 4; ++nb) {
            int col = c0 + wn * 64 + nb * 16 + (lane & 15);
            int obase = wm * 48 + mb * 16 + (lane >> 4) * 4;
            us4v hv;
#pragma unroll
            for (int r = 0; r < 4; ++r)
                hv[r] = f2bf_rne(acc[mb][nb][r] + b_qkv[obase + r]);
            *(us4v*)&qkT[((size_t)n * COLS + col) * 96 + obase] = hv;
        }
    }
}

// ---- k2f: fused attention logits (MFMA over K=2048) + softmax -> att[n,h,u,v] ----
__global__ __launch_bounds__(256) void k2f_att(const unsigned short* __restrict__ qkT,
                                               const float* __restrict__ values,
                                               const float* __restrict__ att_bias,
                                               float* __restrict__ att)
{
    __shared__ unsigned short Qs[32][136], Ks[32][136];
    __shared__ float Ls[32][33];
    int nh = blockIdx.x;
    int n = nh / H_, h = nh % H_;
    int tid = threadIdx.x, lane = tid & 63, wid = tid >> 6;
    int ut = wid >> 1, vt = wid & 1;
    int rbase = lane & 15, koff = (lane >> 4) * 8;

    for (int e = tid; e < 7 * 136; e += 256) {
        int r = 25 + e / 136, c = e % 136;
        Qs[r][c] = 0;
        Ks[r][c] = 0;
    }

    const unsigned short* qbase = qkT + (size_t)n * COLS * 96 + h * 16;
    f32x4 acc = (f32x4)0.f;

    for (int tc = 0; tc < 16; ++tc) {
        __syncthreads();
        for (int L = tid; L < 400; L += 256) {
            int qsel = L / 200, r = L % 200;
            int tt = r / 25, u = r % 25;
            int col = (tc * 8 + tt) * 25 + u;
            const unsigned short* src = qbase + (size_t)col * 96 + qsel * 48;
            ushort8 s0 = *(const ushort8*)&src[0];
            ushort8 s1 = *(const ushort8*)&src[8];
            unsigned short* dst = qsel ? &Ks[u][tt * 16] : &Qs[u][tt * 16];
            *(ushort8*)&dst[0] = s0;
            *(ushort8*)&dst[8] = s1;
        }
        __syncthreads();
#pragma unroll
        for (int ks = 0; ks < 4; ++ks) {
            short8 af = *(const short8*)&Qs[ut * 16 + rbase][ks * 32 + koff];
            short8 bf = *(const short8*)&Ks[vt * 16 + rbase][ks * 32 + koff];
            acc = __builtin_amdgcn_mfma_f32_16x16x32_bf16(af, bf, acc, 0, 0, 0);
        }
    }
    __syncthreads();
#pragma unroll
    for (int r = 0; r < 4; ++r)
        Ls[ut * 16 + (lane >> 4) * 4 + r][vt * 16 + (lane & 15)] = acc[r];
    __syncthreads();
    if (tid < 25) {
        int u = tid;
        float scale = values[h] / 2048.0f;
        float bias = att_bias[h];
        float Lg[25];
        float m = -1e30f;
        for (int v = 0; v < 25; ++v) {
            Lg[v] = Ls[u][v] * scale + bias;
            m = fmaxf(m, Lg[v]);
        }
        float ex[25];
        float s = 0.f;
        for (int v = 0; v < 25; ++v) { ex[v] = expf(Lg[v] - m); s += ex[v]; }
        float inv = 1.0f / s;
        float* ab = att + (size_t)nh * 625 + u * 25;
        for (int v = 0; v < 25; ++v) ab[v] = ex[v] * inv;
    }
}

// ---- k_tmm: Tm via MFMA. Grid N*16 (8 t's per block). TmT[n][col][192] bf16. ----
__global__ __launch_bounds__(256) void k_tmm(const float* __restrict__ x,
                                             const float* __restrict__ att,
                                             unsigned short* __restrict__ tmhi)
{
    __shared__ unsigned short Xc[8 * 64 * 40];    // [tr*64+c][u]
    __shared__ unsigned short attS[3 * 32 * 40];  // [h*32+v][u]
    int blk = blockIdx.x;
    int n = blk >> 4, tg = blk & 15;
    int t0 = tg * 8;
    int tid = threadIdx.x, lane = tid & 63, wid = tid >> 6;
    int rbase = lane & 15, koff = (lane >> 4) * 8;
    const float* xb = x + (size_t)n * 64 * 3200;

    for (int e = tid; e < 3072; e += 256) {
        int tr = e / 384, rem = e % 384;
        int c = rem / 6, j = rem % 6;
        f32x4 v = *(const f32x4*)&xb[(size_t)c * 3200 + (t0 + tr) * 25 + j * 4];
#pragma unroll
        for (int jj = 0; jj < 4; ++jj)
            Xc[(size_t)(tr * 64 + c) * 40 + j * 4 + jj] = f2bf_rne(v[jj]);
    }
    for (int e = tid; e < 512; e += 256) {
        int tr = e / 64, c = e % 64;
        Xc[(size_t)(tr * 64 + c) * 40 + 24] = f2bf_rne(xb[(size_t)c * 3200 + (t0 + tr) * 25 + 24]);
    }
    for (int e = tid; e < 8 * 64 * 7; e += 256) {
        int tr = e / 448, rem = e % 448;
        int c = rem / 7, j = rem % 7;
        Xc[(size_t)(tr * 64 + c) * 40 + 25 + j] = 0;
    }
    const float* ab = att + (size_t)n * 3 * 625;
    for (int e = tid; e < 3 * 32 * 40; e += 256) {
        int h = e / 1280, rem = e % 1280;
        int v = rem / 40, u = rem % 40;
        if (u >= 25 || v >= 25) attS[(size_t)(h * 32 + v) * 40 + u] = 0;
    }
    for (int e = tid; e < 1875; e += 256) {
        int h = e / 625, r = e % 625;
        int u = r / 25, v = r % 25;
        attS[(size_t)(h * 32 + v) * 40 + u] = f2bf_rne(ab[e]);
    }
    __syncthreads();

    unsigned short* tb = tmhi + (size_t)n * COLS * 192;
    for (int i = 0; i < 6; ++i) {
        int pr = wid * 6 + i;
        int tr = pr / 3, h = pr % 3;
        short8 af[2];
#pragma unroll
        for (int vt = 0; vt < 2; ++vt)
            af[vt] = *(const short8*)&attS[(size_t)(h * 32 + vt * 16 + rbase) * 40 + koff];
        f32x4 ac[2][4];
#pragma unroll
        for (int vt = 0; vt < 2; ++vt)
#pragma unroll
            for (int cb = 0; cb < 4; ++cb) ac[vt][cb] = (f32x4)0.f;
#pragma unroll
        for (int cb = 0; cb < 4; ++cb) {
            short8 bf = *(const short8*)&Xc[(size_t)(tr * 64 + cb * 16 + rbase) * 40 + koff];
#pragma unroll
            for (int vt = 0; vt < 2; ++vt)
                ac[vt][cb] = __builtin_amdgcn_mfma_f32_16x16x32_bf16(af[vt], bf, ac[vt][cb], 0, 0, 0);
        }
        int t = t0 + tr;
#pragma unroll
        for (int vt = 0; vt < 2; ++vt) {
#pragma unroll
            for (int cb = 0; cb < 4; ++cb) {
                int c = cb * 16 + (lane & 15);
#pragma unroll
                for (int r = 0; r < 4; ++r) {
                    int v = vt * 16 + (lane >> 4) * 4 + r;
                    if (v < 25)
                        tb[(size_t)(t * 25 + v) * 192 + h * 64 + c] = f2bf_rne(ac[vt][cb][r]);
                }
            }
        }
    }
}

// ---- k34 v4: 512 threads / 8 waves; A-fragments direct from global (L2-resident
//      weights), Bh staged only for Tm; phase 2 barrier-free after X1s fence ----
__global__ __launch_bounds__(512, 1) void k34_mfma(const unsigned short* __restrict__ w3h,
                                                    const unsigned short* __restrict__ w4h,
                                                    const unsigned short* __restrict__ tmhi,
                                                    const float* __restrict__ x,
                                                    const float* __restrict__ b3,
                                                    const float* __restrict__ b4,
                                                    unsigned short* __restrict__ x2hi)
{
    __shared__ unsigned short Bh[128][40];
    __shared__ unsigned short X1s[128][136];
    __shared__ unsigned short Xt[128][72];
    int blk = blockIdx.x;
    int n = blk / 25, ct = blk % 25;
    int c0 = ct * 128;
    int tid = threadIdx.x, lane = tid & 63, wid = tid >> 6;   // wid 0..7
    int wm = wid & 1, wn = wid >> 1;                          // wm 0..1, wn 0..3
    const unsigned short* th = tmhi + (size_t)n * COLS * 192;
    int rbase = lane & 15, koff = (lane >> 4) * 8;
    int arow[4];
#pragma unroll
    for (int mb = 0; mb < 4; ++mb)
        arow[mb] = wm * 64 + mb * 16 + rbase;

    const float* xb = x + (size_t)n * 64 * 3200;
    for (int e = tid; e < 2048; e += 512) {
        int c = e >> 5, f4 = (e & 31) * 4;
        f32x4 v = *(const f32x4*)&xb[(size_t)c * 3200 + c0 + f4];
#pragma unroll
        for (int j = 0; j < 4; ++j)
            Xt[f4 + j][c] = f2bf_rne(v[j]);
    }

    f32x4 acc[4][2];
#pragma unroll
    for (int a = 0; a < 4; ++a)
#pragma unroll
        for (int b = 0; b < 2; ++b) acc[a][b] = (f32x4)0.f;

    // ---- phase 1: x1 = lrelu(W3 . [Tm; x] + b3) -> X1s ----
    for (int ks = 0; ks < 8; ++ks) {
        if (ks < 6) {
            __syncthreads();
            {
                int col = tid >> 2, g = (tid & 3) * 8;
                *(ushort8*)&Bh[col][g] =
                    *(const ushort8*)&th[(size_t)(c0 + col) * 192 + ks * 32 + g];
            }
            __syncthreads();
        }
        short8 afh[4], bfh[2];
#pragma unroll
        for (int mb = 0; mb < 4; ++mb)
            afh[mb] = *(const short8*)&w3h[(size_t)arow[mb] * 256 + ks * 32 + koff];
        if (ks < 6) {
#pragma unroll
            for (int nb = 0; nb < 2; ++nb)
                bfh[nb] = *(const short8*)&Bh[wn * 32 + nb * 16 + rbase][koff];
        } else {
#pragma unroll
            for (int nb = 0; nb < 2; ++nb)
                bfh[nb] = *(const short8*)&Xt[wn * 32 + nb * 16 + rbase][(ks - 6) * 32 + koff];
        }
#pragma unroll
        for (int mb = 0; mb < 4; ++mb)
#pragma unroll
            for (int nb = 0; nb < 2; ++nb)
                acc[mb][nb] = __builtin_amdgcn_mfma_f32_16x16x32_bf16(afh[mb], bfh[nb], acc[mb][nb], 0, 0, 0);
    }
#pragma unroll
    for (int mb = 0; mb < 4; ++mb) {
#pragma unroll
        for (int nb = 0; nb < 2; ++nb) {
            int col = wn * 32 + nb * 16 + (lane & 15);
            int obase = wm * 64 + mb * 16 + (lane >> 4) * 4;
            us4v hv;
#pragma unroll
            for (int r = 0; r < 4; ++r)
                hv[r] = f2bf_rne(lrelu(acc[mb][nb][r] + b3[obase + r]));
            *(us4v*)&X1s[col][obase] = hv;
        }
    }
    __syncthreads();   // X1s visible to all waves

    // ---- phase 2: x2 = lrelu(W4 . [x1; x] + b4) -> x2T  (barrier-free) ----
#pragma unroll
    for (int a = 0; a < 4; ++a)
#pragma unroll
        for (int b = 0; b < 2; ++b) acc[a][b] = (f32x4)0.f;

    for (int ks = 0; ks < 6; ++ks) {
        short8 afh[4], bfh[2];
#pragma unroll
        for (int mb = 0; mb < 4; ++mb)
            afh[mb] = *(const short8*)&w4h[(size_t)arow[mb] * 192 + ks * 32 + koff];
        if (ks < 4) {
#pragma unroll
            for (int nb = 0; nb < 2; ++nb)
                bfh[nb] = *(const short8*)&X1s[wn * 32 + nb * 16 + rbase][ks * 32 + koff];
        } else {
#pragma unroll
            for (int nb = 0; nb < 2; ++nb)
                bfh[nb] = *(const short8*)&Xt[wn * 32 + nb * 16 + rbase][(ks - 4) * 32 + koff];
        }
#pragma unroll
        for (int mb = 0; mb < 4; ++mb)
#pragma unroll
            for (int nb = 0; nb < 2; ++nb)
                acc[mb][nb] = __builtin_amdgcn_mfma_f32_16x16x32_bf16(afh[mb], bfh[nb], acc[mb][nb], 0, 0, 0);
    }
#pragma unroll
    for (int mb = 0; mb < 4; ++mb) {
#pragma unroll
        for (int nb = 0; nb < 2; ++nb) {
            int col = c0 + wn * 32 + nb * 16 + (lane & 15);
            int obase = wm * 64 + mb * 16 + (lane >> 4) * 4;
            us4v hv;
#pragma unroll
            for (int r = 0; r < 4; ++r)
                hv[r] = f2bf_rne(lrelu(acc[mb][nb][r] + b4[obase + r]));
            *(us4v*)&x2hi[((size_t)n * COLS + col) * 128 + obase] = hv;
        }
    }
}

// ---- k5 v8 (reverted): M=64, grid 6400, async gload_lds dbuf, XOR swizzle,
//      epilogue via LDS-transpose -> coalesced dwordx4 stores ----
__global__ __launch_bounds__(256) void k5_mfma(const unsigned short* __restrict__ wAhi,
                                               const unsigned short* __restrict__ x2hiT,
                                               const float* __restrict__ bcomb,
                                               float* __restrict__ out)
{
    __shared__ unsigned short Bh[2][8896];

    int bid = blockIdx.x;
    int swz = (bid & 7) * 800 + (bid >> 3);
    int n = swz / 50;
    int rem = swz - n * 50;
    int ct = rem >> 1, om = rem & 1;
    int c0 = ct * 128;
    int tid = threadIdx.x;
    int lane = tid & 63, wid = tid >> 6;
    int wm = wid & 1, wn = wid >> 1;

    const unsigned short* xb = x2hiT + (size_t)n * 409600;
    int base = c0 - 75;

    if (ct == 0 || ct == 24) {
        for (int L = tid; L < 1112; L += 256) {
            int w = L >> 2;
            int cs = base + w;
            if (cs < 0 || cs >= 3200) {
                *(ushort8*)((char*)&Bh[0][0] + L * 16) = (ushort8)0;
                *(ushort8*)((char*)&Bh[1][0] + L * 16) = (ushort8)0;
            }
        }
    }

    auto LOADB = [&](int buf, int icc) {
#pragma unroll
        for (int j = 0; j < 5; ++j) {
            int L = tid + j * 256;
            if (L < 1112) {
                int w = L >> 2, kcp = L & 3;
                int cs = base + w;
                if (cs >= 0 && cs < 3200) {
                    int kc = kcp ^ ((w >> 1) & 3);
                    gload_lds16(&xb[(size_t)cs * 128 + icc * 32 + kc * 8],
                                (unsigned short*)((char*)&Bh[buf][0] + j * 4096 + wid * 1024));
                }
            }
        }
    };

    f32x4 acc[2][4];
#pragma unroll
    for (int a = 0; a < 2; ++a)
#pragma unroll
        for (int b = 0; b < 4; ++b) acc[a][b] = (f32x4)0.f;

    int rbase = lane & 15;
    int kc = lane >> 4;
    int koff = kc * 8;
    int aoff[2];
#pragma unroll
    for (int mb = 0; mb < 2; ++mb)
        aoff[mb] = (om * 64 + wm * 32 + mb * 16 + rbase) * 1024 + koff;

    LOADB(0, 0);
    __syncthreads();

    for (int ic = 0; ic < 4; ++ic) {
        int i0 = ic * 32;
        int cur = ic & 1;
        short8 afT[8][2];
#pragma unroll
        for (int t = 0; t < 8; ++t)
#pragma unroll
            for (int mb = 0; mb < 2; ++mb)
                afT[t][mb] = *(const short8*)&wAhi[aoff[mb] + t * 128 + i0];
        if (ic < 3) LOADB(cur ^ 1, ic + 1);
#pragma unroll
        for (int tap = 0; tap < 8; ++tap) {
            int wofs = (tap < 7) ? 25 * tap : 75;
            short8 bf[4];
#pragma unroll
            for (int nb = 0; nb < 4; ++nb) {
                int row = wn * 64 + nb * 16 + rbase + wofs;
                int kcs = kc ^ ((row >> 1) & 3);
                bf[nb] = *(const short8*)((const char*)&Bh[cur][0] + row * 64 + kcs * 16);
            }
#pragma unroll
            for (int mb = 0; mb < 2; ++mb)
#pragma unroll
                for (int nb = 0; nb < 4; ++nb)
                    acc[mb][nb] = __builtin_amdgcn_mfma_f32_16x16x32_bf16(afT[tap][mb], bf[nb], acc[mb][nb], 0, 0, 0);
        }
        __syncthreads();
    }

    float* Cs = (float*)&Bh[0][0];
#pragma unroll
    for (int mb = 0; mb < 2; ++mb) {
#pragma unroll
        for (int nb = 0; nb < 4; ++nb) {
            int lc = wn * 64 + nb * 16 + (lane & 15);
            int lr0 = wm * 32 + mb * 16 + (lane >> 4) * 4;
#pragma unroll
            for (int r = 0; r < 4; ++r) {
                int lr = lr0 + r;
                Cs[lr * 132 + lc] = lrelu(acc[mb][nb][r] + bcomb[om * 64 + lr]);
            }
        }
    }
    __syncthreads();
    float* outn = out + ((size_t)n * 128 + om * 64) * 3200 + c0;
#pragma unroll
    for (int s = 0; s < 2; ++s) {
        int row = s * 32 + (tid >> 3);
#pragma unroll
        for (int j = 0; j < 4; ++j) {
            int col = j * 32 + (tid & 7) * 4;
            f32x4 v = *(f32x4*)&Cs[row * 132 + col];
            *(f32x4*)&outn[(size_t)row * 3200 + col] = v;
        }
    }
}

extern "C" void kernel_launch(void* const* d_in, const int* in_sizes, int n_in,
                              void* d_out, int out_size, void* d_ws, size_t ws_size,
                              hipStream_t stream)
{
    const float* x       = (const float*)d_in[0];
    const float* w_qkv   = (const float*)d_in[1];
    const float* b_qkv   = (const float*)d_in[2];
    const float* values  = (const float*)d_in[3];
    const float* att_bias= (const float*)d_in[4];
    const float* w_out   = (const float*)d_in[5];
    const float* b_out   = (const float*)d_in[6];
    const float* g_out   = (const float*)d_in[7];
    const float* be_out  = (const float*)d_in[8];
    const float* m_out   = (const float*)d_in[9];
    const float* v_out   = (const float*)d_in[10];
    const float* w_ff    = (const float*)d_in[11];
    const float* b_ff    = (const float*)d_in[12];
    const float* g_ff    = (const float*)d_in[13];
    const float* be_ff   = (const float*)d_in[14];
    const float* m_ff    = (const float*)d_in[15];
    const float* v_ff    = (const float*)d_in[16];
    const float* w_t     = (const float*)d_in[17];
    const float* b_t     = (const float*)d_in[18];
    const float* g_t     = (const float*)d_in[19];
    const float* be_t    = (const float*)d_in[20];
    const float* m_t     = (const float*)d_in[21];
    const float* v_t     = (const float*)d_in[22];
    const float* w_ress  = (const float*)d_in[23];
    const float* b_ress  = (const float*)d_in[24];
    const float* g_ress  = (const float*)d_in[25];
    const float* be_ress = (const float*)d_in[26];
    const float* m_ress  = (const float*)d_in[27];
    const float* v_ress  = (const float*)d_in[28];
    const float* w_rest  = (const float*)d_in[29];
    const float* b_rest  = (const float*)d_in[30];
    const float* g_rest  = (const float*)d_in[31];
    const float* be_rest = (const float*)d_in[32];
    const float* m_rest  = (const float*)d_in[33];
    const float* v_rest  = (const float*)d_in[34];

    float* ws = (float*)d_ws;
    float* out = (float*)d_out;

    unsigned short* qkT  = (unsigned short*)(ws + OFF_BIG);
    unsigned short* tmhi = (unsigned short*)(ws + OFF_BIG);
    unsigned short* x2hi = (unsigned short*)(ws + OFF_X2);

    k0_prep<<<128, 256, 0, stream>>>(w_qkv,
        w_out, b_out, g_out, be_out, m_out, v_out,
        w_ff, b_ff, g_ff, be_ff, m_ff, v_ff,
        w_t, b_t, g_t, be_t, m_t, v_t,
        w_ress, b_ress, g_ress, be_ress, m_ress, v_ress,
        w_rest, b_rest, g_rest, be_rest, m_rest, v_rest,
        ws);
    k1_mfma<<<N_ * 25, 256, 0, stream>>>(
        (const unsigned short*)(ws + OFF_WQHI), x, b_qkv, qkT);
    k2f_att<<<N_ * H_, 256, 0, stream>>>(qkT, values, att_bias, ws + OFF_ATT);
    k_tmm<<<N_ * 16, 256, 0, stream>>>(x, ws + OFF_ATT, tmhi);
    k34_mfma<<<N_ * 25, 512, 0, stream>>>(
        (const unsigned short*)(ws + OFF_WA3HI), (const unsigned short*)(ws + OFF_WA4HI),
        tmhi, x, ws + OFF_B3, ws + OFF_B4, x2hi);
    k5_mfma<<<N_ * 50, 256, 0, stream>>>(
        (const unsigned short*)(ws + OFF_WA5HI), x2hi, ws + OFF_B5, out);
}

// Round 28
// 524.427 us; speedup vs baseline: 1.1521x; 1.1521x over previous
//
#include <hip/hip_runtime.h>

#define N_  128
#define C_  64
#define T_  128
#define V_  25
#define CO_ 128
#define H_  3
#define D_  16

constexpr int COLS = 3200;
constexpr float EPSF = 1e-5f;

typedef __attribute__((ext_vector_type(8))) short short8;
typedef __attribute__((ext_vector_type(8))) unsigned short ushort8;
typedef __attribute__((ext_vector_type(4))) unsigned short us4v;
typedef __attribute__((ext_vector_type(4))) float f32x4;

// ---- workspace layout (float units) ----
constexpr size_t OFF_ATT  = 0;                          // 240,000
constexpr size_t OFF_BIG  = 240000;                     // time-shared:
//   phase A: qkT bf16 [n][3200][96] (19.7M fl)
//   phase B: TmT bf16 [n][3200][192] (39.3M fl)
constexpr size_t BIGF     = 78643200;
constexpr size_t OFF_X2   = OFF_BIG + BIGF;             // x2T bf16: 26.2M fl
constexpr size_t OFF_W    = OFF_X2 + 26214400;
constexpr size_t OFF_WQHI  = OFF_W;                     // 96*64 us = 3072 fl
constexpr size_t OFF_WA3HI = OFF_WQHI + 3072;           // 128*256 us = 16384 fl
constexpr size_t OFF_WA4HI = OFF_WA3HI + 16384;         // 128*192 us = 12288 fl
constexpr size_t OFF_WA5HI = OFF_WA4HI + 12288;         // 128*1024 us = 65536 fl
constexpr size_t OFF_B3    = OFF_WA5HI + 65536;
constexpr size_t OFF_B4    = OFF_B3 + 128;
constexpr size_t OFF_B5    = OFF_B4 + 128;

__device__ __forceinline__ float lrelu(float y) { return y >= 0.f ? y : 0.1f * y; }

__device__ __forceinline__ unsigned short f2bf_rne(float f) {
    unsigned int u = __builtin_bit_cast(unsigned int, f);
    u += 0x7FFFu + ((u >> 16) & 1u);
    return (unsigned short)(u >> 16);
}
__device__ __forceinline__ float bf2f(unsigned short b) {
    unsigned int u = ((unsigned int)b) << 16;
    return __builtin_bit_cast(float, u);
}

__device__ __forceinline__ void gload_lds16(const unsigned short* g, unsigned short* l) {
    __builtin_amdgcn_global_load_lds(
        (const __attribute__((address_space(1))) unsigned int*)g,
        (__attribute__((address_space(3))) unsigned int*)l,
        16, 0, 0);
}

// ---- K0: BN-fold + bf16 A-operands (single plane) ----
__global__ void k0_prep(const float* __restrict__ w_qkv,
                        const float* __restrict__ w_out, const float* __restrict__ b_out,
                        const float* __restrict__ g_out, const float* __restrict__ be_out,
                        const float* __restrict__ m_out, const float* __restrict__ v_out,
                        const float* __restrict__ w_ff,  const float* __restrict__ b_ff,
                        const float* __restrict__ g_ff,  const float* __restrict__ be_ff,
                        const float* __restrict__ m_ff,  const float* __restrict__ v_ff,
                        const float* __restrict__ w_t,   const float* __restrict__ b_t,
                        const float* __restrict__ g_t,   const float* __restrict__ be_t,
                        const float* __restrict__ m_t,   const float* __restrict__ v_t,
                        const float* __restrict__ w_ress,const float* __restrict__ b_ress,
                        const float* __restrict__ g_ress,const float* __restrict__ be_ress,
                        const float* __restrict__ m_ress,const float* __restrict__ v_ress,
                        const float* __restrict__ w_rest,const float* __restrict__ b_rest,
                        const float* __restrict__ g_rest,const float* __restrict__ be_rest,
                        const float* __restrict__ m_rest,const float* __restrict__ v_rest,
                        float* __restrict__ ws)
{
    int tid = blockIdx.x * blockDim.x + threadIdx.x;
    int np = gridDim.x * blockDim.x;

    unsigned short* wqh = (unsigned short*)(ws + OFF_WQHI);
    for (int idx = tid; idx < 96 * 64; idx += np)
        wqh[idx] = f2bf_rne(w_qkv[idx]);

    unsigned short* w3h = (unsigned short*)(ws + OFF_WA3HI);
    for (int idx = tid; idx < 128 * 256; idx += np) {
        int o = idx >> 8, k = idx & 255;
        float val;
        if (k < 192) {
            float sc = g_out[o] * rsqrtf(v_out[o] + EPSF);
            val = w_out[o * 192 + k] * sc;
        } else {
            float sc = g_ress[o] * rsqrtf(v_ress[o] + EPSF);
            val = w_ress[o * 64 + (k - 192)] * sc;
        }
        w3h[idx] = f2bf_rne(val);
    }

    unsigned short* w4h = (unsigned short*)(ws + OFF_WA4HI);
    for (int idx = tid; idx < 128 * 192; idx += np) {
        int o = idx / 192, k = idx % 192;
        float val;
        if (k < 128) {
            float sc = g_ff[o] * rsqrtf(v_ff[o] + EPSF);
            val = w_ff[o * 128 + k] * sc;
        } else {
            float sc = g_ress[o] * rsqrtf(v_ress[o] + EPSF);
            val = w_ress[o * 64 + (k - 128)] * sc;
        }
        w4h[idx] = f2bf_rne(val);
    }

    unsigned short* w5h = (unsigned short*)(ws + OFF_WA5HI);
    for (int idx = tid; idx < 128 * 1024; idx += np) {
        int o = idx >> 10, kk = idx & 1023;
        int tap = kk >> 7, i = kk & 127;
        float val;
        if (tap < 7) {
            float sc = g_t[o] * rsqrtf(v_t[o] + EPSF);
            val = w_t[((size_t)o * 128 + i) * 7 + tap] * sc;
        } else {
            float sc = g_rest[o] * rsqrtf(v_rest[o] + EPSF);
            val = w_rest[o * 128 + i] * sc;
        }
        w5h[idx] = f2bf_rne(val);
    }

    for (int o = tid; o < 128; o += np) {
        float sco = g_out[o] * rsqrtf(v_out[o] + EPSF);
        float scr = g_ress[o] * rsqrtf(v_ress[o] + EPSF);
        float scf = g_ff[o] * rsqrtf(v_ff[o] + EPSF);
        float sct = g_t[o] * rsqrtf(v_t[o] + EPSF);
        float sce = g_rest[o] * rsqrtf(v_rest[o] + EPSF);
        float bres = (b_ress[o] - m_ress[o]) * scr + be_ress[o];
        ws[OFF_B3 + o] = (b_out[o] - m_out[o]) * sco + be_out[o] + bres;
        ws[OFF_B4 + o] = (b_ff[o] - m_ff[o]) * scf + be_ff[o] + bres;
        ws[OFF_B5 + o] = (b_t[o] - m_t[o]) * sct + be_t[o]
                       + (b_rest[o] - m_rest[o]) * sce + be_rest[o];
    }
}

// ---- k1: qkv GEMM M=96,K=64 -> qkT bf16 [n][3200][96]; x read direct (in-LDS transpose) ----
__global__ __launch_bounds__(256, 2) void k1_mfma(const unsigned short* __restrict__ wqh,
                                                   const float* __restrict__ x,
                                                   const float* __restrict__ b_qkv,
                                                   unsigned short* __restrict__ qkT)
{
    __shared__ unsigned short Ah[96][72];
    __shared__ unsigned short Xt[128][72];
    int blk = blockIdx.x;
    int n = blk / 25, ct = blk % 25;
    int c0 = ct * 128;
    int tid = threadIdx.x, lane = tid & 63, wid = tid >> 6;
    int wm = wid & 1, wn = wid >> 1;
    int rbase = lane & 15, koff = (lane >> 4) * 8;

    for (int e = tid; e < 768; e += 256) {
        int o = e >> 3, g = (e & 7) * 8;
        *(ushort8*)&Ah[o][g] = *(const ushort8*)&wqh[(size_t)o * 64 + g];
    }
    const float* xb = x + (size_t)n * 64 * 3200;
    for (int e = tid; e < 2048; e += 256) {
        int c = e >> 5, f4 = (e & 31) * 4;
        f32x4 v = *(const f32x4*)&xb[(size_t)c * 3200 + c0 + f4];
#pragma unroll
        for (int j = 0; j < 4; ++j)
            Xt[f4 + j][c] = f2bf_rne(v[j]);
    }
    __syncthreads();

    f32x4 acc[3][4];
#pragma unroll
    for (int a = 0; a < 3; ++a)
#pragma unroll
        for (int b = 0; b < 4; ++b) acc[a][b] = (f32x4)0.f;

#pragma unroll
    for (int ks = 0; ks < 2; ++ks) {
        short8 afh[3], bfh[4];
#pragma unroll
        for (int mb = 0; mb < 3; ++mb)
            afh[mb] = *(const short8*)&Ah[wm * 48 + mb * 16 + rbase][ks * 32 + koff];
#pragma unroll
        for (int nb = 0; nb < 4; ++nb)
            bfh[nb] = *(const short8*)&Xt[wn * 64 + nb * 16 + rbase][ks * 32 + koff];
#pragma unroll
        for (int mb = 0; mb < 3; ++mb)
#pragma unroll
            for (int nb = 0; nb < 4; ++nb)
                acc[mb][nb] = __builtin_amdgcn_mfma_f32_16x16x32_bf16(afh[mb], bfh[nb], acc[mb][nb], 0, 0, 0);
    }
#pragma unroll
    for (int mb = 0; mb < 3; ++mb) {
#pragma unroll
        for (int nb = 0; nb < 4; ++nb) {
            int col = c0 + wn * 64 + nb * 16 + (lane & 15);
            int obase = wm * 48 + mb * 16 + (lane >> 4) * 4;
            us4v hv;
#pragma unroll
            for (int r = 0; r < 4; ++r)
                hv[r] = f2bf_rne(acc[mb][nb][r] + b_qkv[obase + r]);
            *(us4v*)&qkT[((size_t)n * COLS + col) * 96 + obase] = hv;
        }
    }
}

// ---- k2f: fused attention logits (MFMA over K=2048) + softmax -> att[n,h,u,v] ----
__global__ __launch_bounds__(256) void k2f_att(const unsigned short* __restrict__ qkT,
                                               const float* __restrict__ values,
                                               const float* __restrict__ att_bias,
                                               float* __restrict__ att)
{
    __shared__ unsigned short Qs[32][136], Ks[32][136];
    __shared__ float Ls[32][33];
    int nh = blockIdx.x;
    int n = nh / H_, h = nh % H_;
    int tid = threadIdx.x, lane = tid & 63, wid = tid >> 6;
    int ut = wid >> 1, vt = wid & 1;
    int rbase = lane & 15, koff = (lane >> 4) * 8;

    for (int e = tid; e < 7 * 136; e += 256) {
        int r = 25 + e / 136, c = e % 136;
        Qs[r][c] = 0;
        Ks[r][c] = 0;
    }

    const unsigned short* qbase = qkT + (size_t)n * COLS * 96 + h * 16;
    f32x4 acc = (f32x4)0.f;

    for (int tc = 0; tc < 16; ++tc) {
        __syncthreads();
        for (int L = tid; L < 400; L += 256) {
            int qsel = L / 200, r = L % 200;
            int tt = r / 25, u = r % 25;
            int col = (tc * 8 + tt) * 25 + u;
            const unsigned short* src = qbase + (size_t)col * 96 + qsel * 48;
            ushort8 s0 = *(const ushort8*)&src[0];
            ushort8 s1 = *(const ushort8*)&src[8];
            unsigned short* dst = qsel ? &Ks[u][tt * 16] : &Qs[u][tt * 16];
            *(ushort8*)&dst[0] = s0;
            *(ushort8*)&dst[8] = s1;
        }
        __syncthreads();
#pragma unroll
        for (int ks = 0; ks < 4; ++ks) {
            short8 af = *(const short8*)&Qs[ut * 16 + rbase][ks * 32 + koff];
            short8 bf = *(const short8*)&Ks[vt * 16 + rbase][ks * 32 + koff];
            acc = __builtin_amdgcn_mfma_f32_16x16x32_bf16(af, bf, acc, 0, 0, 0);
        }
    }
    __syncthreads();
#pragma unroll
    for (int r = 0; r < 4; ++r)
        Ls[ut * 16 + (lane >> 4) * 4 + r][vt * 16 + (lane & 15)] = acc[r];
    __syncthreads();
    if (tid < 25) {
        int u = tid;
        float scale = values[h] / 2048.0f;
        float bias = att_bias[h];
        float Lg[25];
        float m = -1e30f;
        for (int v = 0; v < 25; ++v) {
            Lg[v] = Ls[u][v] * scale + bias;
            m = fmaxf(m, Lg[v]);
        }
        float ex[25];
        float s = 0.f;
        for (int v = 0; v < 25; ++v) { ex[v] = expf(Lg[v] - m); s += ex[v]; }
        float inv = 1.0f / s;
        float* ab = att + (size_t)nh * 625 + u * 25;
        for (int v = 0; v < 25; ++v) ab[v] = ex[v] * inv;
    }
}

// ---- k_tmm: Tm via MFMA. Grid N*16 (8 t's per block). TmT[n][col][192] bf16. ----
__global__ __launch_bounds__(256) void k_tmm(const float* __restrict__ x,
                                             const float* __restrict__ att,
                                             unsigned short* __restrict__ tmhi)
{
    __shared__ unsigned short Xc[8 * 64 * 40];    // [tr*64+c][u]
    __shared__ unsigned short attS[3 * 32 * 40];  // [h*32+v][u]
    int blk = blockIdx.x;
    int n = blk >> 4, tg = blk & 15;
    int t0 = tg * 8;
    int tid = threadIdx.x, lane = tid & 63, wid = tid >> 6;
    int rbase = lane & 15, koff = (lane >> 4) * 8;
    const float* xb = x + (size_t)n * 64 * 3200;

    for (int e = tid; e < 3072; e += 256) {
        int tr = e / 384, rem = e % 384;
        int c = rem / 6, j = rem % 6;
        f32x4 v = *(const f32x4*)&xb[(size_t)c * 3200 + (t0 + tr) * 25 + j * 4];
#pragma unroll
        for (int jj = 0; jj < 4; ++jj)
            Xc[(size_t)(tr * 64 + c) * 40 + j * 4 + jj] = f2bf_rne(v[jj]);
    }
    for (int e = tid; e < 512; e += 256) {
        int tr = e / 64, c = e % 64;
        Xc[(size_t)(tr * 64 + c) * 40 + 24] = f2bf_rne(xb[(size_t)c * 3200 + (t0 + tr) * 25 + 24]);
    }
    for (int e = tid; e < 8 * 64 * 7; e += 256) {
        int tr = e / 448, rem = e % 448;
        int c = rem / 7, j = rem % 7;
        Xc[(size_t)(tr * 64 + c) * 40 + 25 + j] = 0;
    }
    const float* ab = att + (size_t)n * 3 * 625;
    for (int e = tid; e < 3 * 32 * 40; e += 256) {
        int h = e / 1280, rem = e % 1280;
        int v = rem / 40, u = rem % 40;
        if (u >= 25 || v >= 25) attS[(size_t)(h * 32 + v) * 40 + u] = 0;
    }
    for (int e = tid; e < 1875; e += 256) {
        int h = e / 625, r = e % 625;
        int u = r / 25, v = r % 25;
        attS[(size_t)(h * 32 + v) * 40 + u] = f2bf_rne(ab[e]);
    }
    __syncthreads();

    unsigned short* tb = tmhi + (size_t)n * COLS * 192;
    for (int i = 0; i < 6; ++i) {
        int pr = wid * 6 + i;
        int tr = pr / 3, h = pr % 3;
        short8 af[2];
#pragma unroll
        for (int vt = 0; vt < 2; ++vt)
            af[vt] = *(const short8*)&attS[(size_t)(h * 32 + vt * 16 + rbase) * 40 + koff];
        f32x4 ac[2][4];
#pragma unroll
        for (int vt = 0; vt < 2; ++vt)
#pragma unroll
            for (int cb = 0; cb < 4; ++cb) ac[vt][cb] = (f32x4)0.f;
#pragma unroll
        for (int cb = 0; cb < 4; ++cb) {
            short8 bf = *(const short8*)&Xc[(size_t)(tr * 64 + cb * 16 + rbase) * 40 + koff];
#pragma unroll
            for (int vt = 0; vt < 2; ++vt)
                ac[vt][cb] = __builtin_amdgcn_mfma_f32_16x16x32_bf16(af[vt], bf, ac[vt][cb], 0, 0, 0);
        }
        int t = t0 + tr;
#pragma unroll
        for (int vt = 0; vt < 2; ++vt) {
#pragma unroll
            for (int cb = 0; cb < 4; ++cb) {
                int c = cb * 16 + (lane & 15);
#pragma unroll
                for (int r = 0; r < 4; ++r) {
                    int v = vt * 16 + (lane >> 4) * 4 + r;
                    if (v < 25)
                        tb[(size_t)(t * 25 + v) * 192 + h * 64 + c] = f2bf_rne(ac[vt][cb][r]);
                }
            }
        }
    }
}

// ---- k34 v3: 512 threads / 8 waves (2x4 wave grid), 128x128 tile ----
__global__ __launch_bounds__(512, 1) void k34_mfma(const unsigned short* __restrict__ w3h,
                                                    const unsigned short* __restrict__ w4h,
                                                    const unsigned short* __restrict__ tmhi,
                                                    const float* __restrict__ x,
                                                    const float* __restrict__ b3,
                                                    const float* __restrict__ b4,
                                                    unsigned short* __restrict__ x2hi)
{
    __shared__ unsigned short Ah[128][40], Bh[128][40];
    __shared__ unsigned short X1s[128][136];
    __shared__ unsigned short Xt[128][72];
    int blk = blockIdx.x;
    int n = blk / 25, ct = blk % 25;
    int c0 = ct * 128;
    int tid = threadIdx.x, lane = tid & 63, wid = tid >> 6;   // wid 0..7
    int wm = wid & 1, wn = wid >> 1;                          // wm 0..1, wn 0..3
    const unsigned short* th = tmhi + (size_t)n * COLS * 192;
    int rbase = lane & 15, koff = (lane >> 4) * 8;

    const float* xb = x + (size_t)n * 64 * 3200;
    for (int e = tid; e < 2048; e += 512) {
        int c = e >> 5, f4 = (e & 31) * 4;
        f32x4 v = *(const f32x4*)&xb[(size_t)c * 3200 + c0 + f4];
#pragma unroll
        for (int j = 0; j < 4; ++j)
            Xt[f4 + j][c] = f2bf_rne(v[j]);
    }

    f32x4 acc[4][2];
#pragma unroll
    for (int a = 0; a < 4; ++a)
#pragma unroll
        for (int b = 0; b < 2; ++b) acc[a][b] = (f32x4)0.f;

    for (int ks = 0; ks < 8; ++ks) {
        __syncthreads();
        {
            int L = tid;
            int o = L >> 2, g = (L & 3) * 8;
            *(ushort8*)&Ah[o][g] = *(const ushort8*)&w3h[(size_t)o * 256 + ks * 32 + g];
        }
        if (ks < 6) {
            int L = tid;
            int col = L >> 2, g = (L & 3) * 8;
            *(ushort8*)&Bh[col][g] =
                *(const ushort8*)&th[(size_t)(c0 + col) * 192 + ks * 32 + g];
        }
        __syncthreads();
        short8 afh[4], bfh[2];
#pragma unroll
        for (int mb = 0; mb < 4; ++mb)
            afh[mb] = *(const short8*)&Ah[wm * 64 + mb * 16 + rbase][koff];
        if (ks < 6) {
#pragma unroll
            for (int nb = 0; nb < 2; ++nb)
                bfh[nb] = *(const short8*)&Bh[wn * 32 + nb * 16 + rbase][koff];
        } else {
#pragma unroll
            for (int nb = 0; nb < 2; ++nb)
                bfh[nb] = *(const short8*)&Xt[wn * 32 + nb * 16 + rbase][(ks - 6) * 32 + koff];
        }
#pragma unroll
        for (int mb = 0; mb < 4; ++mb)
#pragma unroll
            for (int nb = 0; nb < 2; ++nb)
                acc[mb][nb] = __builtin_amdgcn_mfma_f32_16x16x32_bf16(afh[mb], bfh[nb], acc[mb][nb], 0, 0, 0);
    }
#pragma unroll
    for (int mb = 0; mb < 4; ++mb) {
#pragma unroll
        for (int nb = 0; nb < 2; ++nb) {
            int col = wn * 32 + nb * 16 + (lane & 15);
            int obase = wm * 64 + mb * 16 + (lane >> 4) * 4;
            us4v hv;
#pragma unroll
            for (int r = 0; r < 4; ++r)
                hv[r] = f2bf_rne(lrelu(acc[mb][nb][r] + b3[obase + r]));
            *(us4v*)&X1s[col][obase] = hv;
        }
    }

#pragma unroll
    for (int a = 0; a < 4; ++a)
#pragma unroll
        for (int b = 0; b < 2; ++b) acc[a][b] = (f32x4)0.f;

    for (int ks = 0; ks < 6; ++ks) {
        __syncthreads();
        {
            int L = tid;
            int o = L >> 2, g = (L & 3) * 8;
            *(ushort8*)&Ah[o][g] = *(const ushort8*)&w4h[(size_t)o * 192 + ks * 32 + g];
        }
        __syncthreads();
        short8 afh[4], bfh[2];
#pragma unroll
        for (int mb = 0; mb < 4; ++mb)
            afh[mb] = *(const short8*)&Ah[wm * 64 + mb * 16 + rbase][koff];
        if (ks < 4) {
#pragma unroll
            for (int nb = 0; nb < 2; ++nb)
                bfh[nb] = *(const short8*)&X1s[wn * 32 + nb * 16 + rbase][ks * 32 + koff];
        } else {
#pragma unroll
            for (int nb = 0; nb < 2; ++nb)
                bfh[nb] = *(const short8*)&Xt[wn * 32 + nb * 16 + rbase][(ks - 4) * 32 + koff];
        }
#pragma unroll
        for (int mb = 0; mb < 4; ++mb)
#pragma unroll
            for (int nb = 0; nb < 2; ++nb)
                acc[mb][nb] = __builtin_amdgcn_mfma_f32_16x16x32_bf16(afh[mb], bfh[nb], acc[mb][nb], 0, 0, 0);
    }
#pragma unroll
    for (int mb = 0; mb < 4; ++mb) {
#pragma unroll
        for (int nb = 0; nb < 2; ++nb) {
            int col = c0 + wn * 32 + nb * 16 + (lane & 15);
            int obase = wm * 64 + mb * 16 + (lane >> 4) * 4;
            us4v hv;
#pragma unroll
            for (int r = 0; r < 4; ++r)
                hv[r] = f2bf_rne(lrelu(acc[mb][nb][r] + b4[obase + r]));
            *(us4v*)&x2hi[((size_t)n * COLS + col) * 128 + obase] = hv;
        }
    }
}

// ---- k5 v8: M=64, grid 6400, async gload_lds dbuf, XOR swizzle,
//      epilogue via LDS-transpose -> coalesced dwordx4 stores ----
__global__ __launch_bounds__(256) void k5_mfma(const unsigned short* __restrict__ wAhi,
                                               const unsigned short* __restrict__ x2hiT,
                                               const float* __restrict__ bcomb,
                                               float* __restrict__ out)
{
    __shared__ unsigned short Bh[2][8896];

    int bid = blockIdx.x;
    int swz = (bid & 7) * 800 + (bid >> 3);
    int n = swz / 50;
    int rem = swz - n * 50;
    int ct = rem >> 1, om = rem & 1;
    int c0 = ct * 128;
    int tid = threadIdx.x;
    int lane = tid & 63, wid = tid >> 6;
    int wm = wid & 1, wn = wid >> 1;

    const unsigned short* xb = x2hiT + (size_t)n * 409600;
    int base = c0 - 75;

    if (ct == 0 || ct == 24) {
        for (int L = tid; L < 1112; L += 256) {
            int w = L >> 2;
            int cs = base + w;
            if (cs < 0 || cs >= 3200) {
                *(ushort8*)((char*)&Bh[0][0] + L * 16) = (ushort8)0;
                *(ushort8*)((char*)&Bh[1][0] + L * 16) = (ushort8)0;
            }
        }
    }

    auto LOADB = [&](int buf, int icc) {
#pragma unroll
        for (int j = 0; j < 5; ++j) {
            int L = tid + j * 256;
            if (L < 1112) {
                int w = L >> 2, kcp = L & 3;
                int cs = base + w;
                if (cs >= 0 && cs < 3200) {
                    int kc = kcp ^ ((w >> 1) & 3);
                    gload_lds16(&xb[(size_t)cs * 128 + icc * 32 + kc * 8],
                                (unsigned short*)((char*)&Bh[buf][0] + j * 4096 + wid * 1024));
                }
            }
        }
    };

    f32x4 acc[2][4];
#pragma unroll
    for (int a = 0; a < 2; ++a)
#pragma unroll
        for (int b = 0; b < 4; ++b) acc[a][b] = (f32x4)0.f;

    int rbase = lane & 15;
    int kc = lane >> 4;
    int koff = kc * 8;
    int aoff[2];
#pragma unroll
    for (int mb = 0; mb < 2; ++mb)
        aoff[mb] = (om * 64 + wm * 32 + mb * 16 + rbase) * 1024 + koff;

    LOADB(0, 0);
    __syncthreads();

    for (int ic = 0; ic < 4; ++ic) {
        int i0 = ic * 32;
        int cur = ic & 1;
        short8 afT[8][2];
#pragma unroll
        for (int t = 0; t < 8; ++t)
#pragma unroll
            for (int mb = 0; mb < 2; ++mb)
                afT[t][mb] = *(const short8*)&wAhi[aoff[mb] + t * 128 + i0];
        if (ic < 3) LOADB(cur ^ 1, ic + 1);
#pragma unroll
        for (int tap = 0; tap < 8; ++tap) {
            int wofs = (tap < 7) ? 25 * tap : 75;
            short8 bf[4];
#pragma unroll
            for (int nb = 0; nb < 4; ++nb) {
                int row = wn * 64 + nb * 16 + rbase + wofs;
                int kcs = kc ^ ((row >> 1) & 3);
                bf[nb] = *(const short8*)((const char*)&Bh[cur][0] + row * 64 + kcs * 16);
            }
#pragma unroll
            for (int mb = 0; mb < 2; ++mb)
#pragma unroll
                for (int nb = 0; nb < 4; ++nb)
                    acc[mb][nb] = __builtin_amdgcn_mfma_f32_16x16x32_bf16(afT[tap][mb], bf[nb], acc[mb][nb], 0, 0, 0);
        }
        __syncthreads();
    }

    float* Cs = (float*)&Bh[0][0];
#pragma unroll
    for (int mb = 0; mb < 2; ++mb) {
#pragma unroll
        for (int nb = 0; nb < 4; ++nb) {
            int lc = wn * 64 + nb * 16 + (lane & 15);
            int lr0 = wm * 32 + mb * 16 + (lane >> 4) * 4;
#pragma unroll
            for (int r = 0; r < 4; ++r) {
                int lr = lr0 + r;
                Cs[lr * 132 + lc] = lrelu(acc[mb][nb][r] + bcomb[om * 64 + lr]);
            }
        }
    }
    __syncthreads();
    float* outn = out + ((size_t)n * 128 + om * 64) * 3200 + c0;
#pragma unroll
    for (int s = 0; s < 2; ++s) {
        int row = s * 32 + (tid >> 3);
#pragma unroll
        for (int j = 0; j < 4; ++j) {
            int col = j * 32 + (tid & 7) * 4;
            f32x4 v = *(f32x4*)&Cs[row * 132 + col];
            *(f32x4*)&outn[(size_t)row * 3200 + col] = v;
        }
    }
}

extern "C" void kernel_launch(void* const* d_in, const int* in_sizes, int n_in,
                              void* d_out, int out_size, void* d_ws, size_t ws_size,
                              hipStream_t stream)
{
    const float* x       = (const float*)d_in[0];
    const float* w_qkv   = (const float*)d_in[1];
    const float* b_qkv   = (const float*)d_in[2];
    const float* values  = (const float*)d_in[3];
    const float* att_bias= (const float*)d_in[4];
    const float* w_out   = (const float*)d_in[5];
    const float* b_out   = (const float*)d_in[6];
    const float* g_out   = (const float*)d_in[7];
    const float* be_out  = (const float*)d_in[8];
    const float* m_out   = (const float*)d_in[9];
    const float* v_out   = (const float*)d_in[10];
    const float* w_ff    = (const float*)d_in[11];
    const float* b_ff    = (const float*)d_in[12];
    const float* g_ff    = (const float*)d_in[13];
    const float* be_ff   = (const float*)d_in[14];
    const float* m_ff    = (const float*)d_in[15];
    const float* v_ff    = (const float*)d_in[16];
    const float* w_t     = (const float*)d_in[17];
    const float* b_t     = (const float*)d_in[18];
    const float* g_t     = (const float*)d_in[19];
    const float* be_t    = (const float*)d_in[20];
    const float* m_t     = (const float*)d_in[21];
    const float* v_t     = (const float*)d_in[22];
    const float* w_ress  = (const float*)d_in[23];
    const float* b_ress  = (const float*)d_in[24];
    const float* g_ress  = (const float*)d_in[25];
    const float* be_ress = (const float*)d_in[26];
    const float* m_ress  = (const float*)d_in[27];
    const float* v_ress  = (const float*)d_in[28];
    const float* w_rest  = (const float*)d_in[29];
    const float* b_rest  = (const float*)d_in[30];
    const float* g_rest  = (const float*)d_in[31];
    const float* be_rest = (const float*)d_in[32];
    const float* m_rest  = (const float*)d_in[33];
    const float* v_rest  = (const float*)d_in[34];

    float* ws = (float*)d_ws;
    float* out = (float*)d_out;

    unsigned short* qkT  = (unsigned short*)(ws + OFF_BIG);
    unsigned short* tmhi = (unsigned short*)(ws + OFF_BIG);
    unsigned short* x2hi = (unsigned short*)(ws + OFF_X2);

    k0_prep<<<128, 256, 0, stream>>>(w_qkv,
        w_out, b_out, g_out, be_out, m_out, v_out,
        w_ff, b_ff, g_ff, be_ff, m_ff, v_ff,
        w_t, b_t, g_t, be_t, m_t, v_t,
        w_ress, b_ress, g_ress, be_ress, m_ress, v_ress,
        w_rest, b_rest, g_rest, be_rest, m_rest, v_rest,
        ws);
    k1_mfma<<<N_ * 25, 256, 0, stream>>>(
        (const unsigned short*)(ws + OFF_WQHI), x, b_qkv, qkT);
    k2f_att<<<N_ * H_, 256, 0, stream>>>(qkT, values, att_bias, ws + OFF_ATT);
    k_tmm<<<N_ * 16, 256, 0, stream>>>(x, ws + OFF_ATT, tmhi);
    k34_mfma<<<N_ * 25, 512, 0, stream>>>(
        (const unsigned short*)(ws + OFF_WA3HI), (const unsigned short*)(ws + OFF_WA4HI),
        tmhi, x, ws + OFF_B3, ws + OFF_B4, x2hi);
    k5_mfma<<<N_ * 50, 256, 0, stream>>>(
        (const unsigned short*)(ws + OFF_WA5HI), x2hi, ws + OFF_B5, out);
}